// Round 1
// baseline (34.238 us; speedup 1.0000x reference)
//
#include <hip/hip_runtime.h>
#include <math.h>

// DOSAConLoss: out = mean(base) * mean(density_weight)
//   base_i = (1 - ciou_i)^3 / (target_area_i + 1e-7)
//   mean(density_weight) = 1 + 1.5 * (N / max_hist) / 1024   (since sum(hist)=N)
//
// K1: stream 128MB, compute base, LDS histogram -> per-block partials (no global atomics)
// K2: reduce partial histograms -> finalHist[1024]
// K3: max(finalHist) + sum(double partials) -> scalar

#define NPART 256
#define GRID_BINS 1024

constexpr float EPSF = 1e-7f;

__global__ __launch_bounds__(1024) void dosa_main(
    const float4* __restrict__ pred, const float4* __restrict__ tgt, int n,
    unsigned* __restrict__ partHist, double* __restrict__ partSum)
{
    __shared__ unsigned lhist[GRID_BINS];
    __shared__ double sdsum[1024];
    for (int i = threadIdx.x; i < GRID_BINS; i += blockDim.x) lhist[i] = 0u;
    __syncthreads();

    float fsum = 0.0f;
    const int stride = gridDim.x * blockDim.x;
    for (int i = blockIdx.x * blockDim.x + threadIdx.x; i < n; i += stride) {
        float4 p = pred[i];
        float4 t = tgt[i];
        float x1 = p.x, y1 = p.y, w1 = p.z, h1 = p.w;
        float x2 = t.x, y2 = t.y, w2 = t.z, h2 = t.w;
        // xywh -> xyxy
        float b1x1 = x1 - w1 * 0.5f, b1x2 = x1 + w1 * 0.5f;
        float b1y1 = y1 - h1 * 0.5f, b1y2 = y1 + h1 * 0.5f;
        float b2x1 = x2 - w2 * 0.5f, b2x2 = x2 + w2 * 0.5f;
        float b2y1 = y2 - h2 * 0.5f, b2y2 = y2 + h2 * 0.5f;
        // intersection / union / iou
        float iw = fminf(b1x2, b2x2) - fmaxf(b1x1, b2x1); iw = fmaxf(iw, 0.0f);
        float ih = fminf(b1y2, b2y2) - fmaxf(b1y1, b2y1); ih = fmaxf(ih, 0.0f);
        float inter = iw * ih;
        float uni = w1 * h1 + w2 * h2 - inter + EPSF;
        float iou = inter / uni;
        // enclosing box diag + center distance
        float cw = fmaxf(b1x2, b2x2) - fminf(b1x1, b2x1);
        float ch = fmaxf(b1y2, b2y2) - fminf(b1y1, b2y1);
        float c2 = cw * cw + ch * ch + EPSF;
        float ddx = b2x1 + b2x2 - b1x1 - b1x2;
        float ddy = b2y1 + b2y2 - b1y1 - b1y2;
        float rho2 = (ddx * ddx + ddy * ddy) * 0.25f;
        // aspect-ratio term
        float dv = atanf(w2 / h2) - atanf(w1 / h1);
        float v = 0.4052847345693511f * (dv * dv);   // 4/pi^2
        float a = v / (v - iou + (1.0f + EPSF));
        float ciou = iou - (rho2 / c2 + v * a);
        float om = 1.0f - ciou;
        float base = om * om * om / (w2 * h2 + 1e-7f);
        fsum += base;
        // density histogram over target centers
        int gx = (int)(x2 * 32.0f); gx = min(max(gx, 0), 31);
        int gy = (int)(y2 * 32.0f); gy = min(max(gy, 0), 31);
        atomicAdd(&lhist[gy * 32 + gx], 1u);
    }
    __syncthreads();
    for (int i = threadIdx.x; i < GRID_BINS; i += blockDim.x)
        partHist[(size_t)blockIdx.x * GRID_BINS + i] = lhist[i];
    sdsum[threadIdx.x] = (double)fsum;
    __syncthreads();
    for (int off = 512; off > 0; off >>= 1) {
        if (threadIdx.x < off) sdsum[threadIdx.x] += sdsum[threadIdx.x + off];
        __syncthreads();
    }
    if (threadIdx.x == 0) partSum[blockIdx.x] = sdsum[0];
}

__global__ __launch_bounds__(NPART) void dosa_hist_reduce(
    const unsigned* __restrict__ partHist, unsigned* __restrict__ finalHist)
{
    __shared__ unsigned s[NPART];
    int bin = blockIdx.x;
    s[threadIdx.x] = partHist[(size_t)threadIdx.x * GRID_BINS + bin];
    __syncthreads();
    for (int off = NPART / 2; off > 0; off >>= 1) {
        if (threadIdx.x < off) s[threadIdx.x] += s[threadIdx.x + off];
        __syncthreads();
    }
    if (threadIdx.x == 0) finalHist[bin] = s[0];
}

__global__ __launch_bounds__(1024) void dosa_final(
    const unsigned* __restrict__ finalHist, const double* __restrict__ partSum,
    float* __restrict__ out, int n)
{
    __shared__ unsigned sm[1024];
    __shared__ double sd[1024];
    int t = threadIdx.x;
    sm[t] = finalHist[t];
    sd[t] = (t < NPART) ? partSum[t] : 0.0;
    __syncthreads();
    for (int off = 512; off > 0; off >>= 1) {
        if (t < off) {
            sm[t] = max(sm[t], sm[t + off]);
            sd[t] += sd[t + off];
        }
        __syncthreads();
    }
    if (t == 0) {
        double meanBase = sd[0] / (double)n;
        double meanW = 1.0 + 1.5 * ((double)n / (double)sm[0]) / 1024.0;
        out[0] = (float)(meanBase * meanW);
    }
}

extern "C" void kernel_launch(void* const* d_in, const int* in_sizes, int n_in,
                              void* d_out, int out_size, void* d_ws, size_t ws_size,
                              hipStream_t stream) {
    const float4* pred = (const float4*)d_in[0];
    const float4* tgt  = (const float4*)d_in[1];
    int n = in_sizes[0] / 4;

    unsigned* partHist = (unsigned*)d_ws;
    double*   partSum  = (double*)((char*)d_ws + (size_t)NPART * GRID_BINS * 4);
    unsigned* finalHist = (unsigned*)((char*)d_ws + (size_t)NPART * GRID_BINS * 4 + NPART * 8);
    float* out = (float*)d_out;

    dosa_main<<<NPART, 1024, 0, stream>>>(pred, tgt, n, partHist, partSum);
    dosa_hist_reduce<<<GRID_BINS, NPART, 0, stream>>>(partHist, finalHist);
    dosa_final<<<1, 1024, 0, stream>>>(finalHist, partSum, out, n);
}